// Round 2
// baseline (1237.935 us; speedup 1.0000x reference)
//
#include <hip/hip_runtime.h>
#include <hip/hip_fp16.h>

#define L_    2048
#define D_    64
#define QT    64
#define NKT   32            // 2048 / 64
#define PBP   72            // u16 pitch for Pbuf rows

typedef _Float16 half8  __attribute__((ext_vector_type(8)));
typedef _Float16 half4  __attribute__((ext_vector_type(4)));
typedef float    f32x4  __attribute__((ext_vector_type(4)));

__device__ __forceinline__ f32x4 mfma16f(half8 a, half8 b, f32x4 c) {
    return __builtin_amdgcn_mfma_f32_16x16x32_f16(a, b, c, 0, 0, 0);
}

// ---------------- pre-pass: K fp32 -> fp16 (same layout) ----------------
__global__ __launch_bounds__(256)
void cvt_k(const float* __restrict__ Kg, _Float16* __restrict__ Kh)
{
    // 2*16*2048*64 = 4,194,304 f32 = 1,048,576 f32x4 chunks; 1024 blk * 256 thr * 4
    const int base = blockIdx.x * 1024 + threadIdx.x;
#pragma unroll
    for (int j = 0; j < 4; ++j) {
        const size_t c = (size_t)base + (size_t)j * 256;
        f32x4 x = ((const f32x4*)Kg)[c];
        half4 h;
#pragma unroll
        for (int e = 0; e < 4; ++e) h[e] = (_Float16)x[e];
        ((half4*)Kh)[c] = h;
    }
}

// ---------------- pre-pass: V fp32 [bh][k][d] -> fp16 transposed [bh][d][k] ----------------
__global__ __launch_bounds__(256)
void tr_v(const float* __restrict__ Vg, _Float16* __restrict__ Vth)
{
    __shared__ float t[64][65];
    const int bh = blockIdx.x >> 5;
    const int kt = blockIdx.x & 31;
    const float* src = Vg + ((size_t)bh * L_ + (size_t)kt * 64) * D_;
    const int tid = threadIdx.x;
#pragma unroll
    for (int j = 0; j < 4; ++j) {
        const int k = j * 16 + (tid >> 4);
        const int d = (tid & 15) * 4;
        f32x4 x = *(const f32x4*)(src + k * 64 + d);
#pragma unroll
        for (int e = 0; e < 4; ++e) t[d + e][k] = x[e];
    }
    __syncthreads();
    _Float16* dst = Vth + (size_t)bh * 64 * L_ + (size_t)kt * 64;
#pragma unroll
    for (int j = 0; j < 4; ++j) {
        const int d = j * 16 + (tid >> 4);
        const int k = (tid & 15) * 4;
        half4 h;
#pragma unroll
        for (int e = 0; e < 4; ++e) h[e] = (_Float16)t[d][k + e];
        *(half4*)(dst + (size_t)d * L_ + k) = h;
    }
}

// ---------------- main fused kernel: no LDS staging, frags direct from L2 ----------------
template<bool WS>
__global__ __launch_bounds__(256, 4)
void attn_fused(const float* __restrict__ Qg, const float* __restrict__ Kg,
                const float* __restrict__ Vg, const int* __restrict__ validg,
                const float* __restrict__ scaleg,
                const _Float16* __restrict__ Khg, const _Float16* __restrict__ Vthg,
                float* __restrict__ outR, float* __restrict__ outW)
{
    // wave-private P round-trip buffer (A-frag relayout); no cross-wave sharing -> no barriers
    __shared__ __attribute__((aligned(16))) _Float16 Pbuf[64 * PBP];    // 9216 B

    const int tid  = threadIdx.x;
    const int wv   = tid >> 6;
    const int lane = tid & 63;
    const int ln   = lane & 15;
    const int qd   = lane >> 4;

    // XCD-grouping swizzle: 4 bh per XCD -> K/V L2-resident per XCD
    const int bidx = blockIdx.x;
    const int bh   = (bidx & 7) * 4 + ((bidx >> 3) & 3);
    const int qt   = bidx >> 5;

    const float scale = scaleg[0];

    const float* Qb = Qg + ((size_t)bh * L_ + (size_t)qt * QT) * D_;
    const float* Kb = Kg + (size_t)bh * L_ * D_;
    const float* Vb = Vg + (size_t)bh * L_ * D_;
    const _Float16* Khb  = Khg  ? Khg  + (size_t)bh * L_ * D_ : nullptr;
    const _Float16* Vthb = Vthg ? Vthg + (size_t)bh * D_ * L_ : nullptr;
    const int*   Mb = validg + ((size_t)bh * L_ + (size_t)qt * QT) * (size_t)L_;
    float* Ob = outR + ((size_t)bh * L_ + (size_t)qt * QT) * D_;
    float* Wb = outW + ((size_t)bh * L_ + (size_t)qt * QT) * (size_t)L_;

    // ---- persistent Q A-fragments (fp16): A[m=ln][k=qd*8+j], frag f: d = f*32.. ----
    half8 aF[2];
    {
        const float* qrow = Qb + (size_t)(wv * 16 + ln) * D_;
#pragma unroll
        for (int f = 0; f < 2; ++f) {
            f32x4 x0 = *(const f32x4*)(qrow + f * 32 + qd * 8);
            f32x4 x1 = *(const f32x4*)(qrow + f * 32 + qd * 8 + 4);
            half8 h;
#pragma unroll
            for (int j = 0; j < 4; ++j) { h[j] = (_Float16)x0[j]; h[4 + j] = (_Float16)x1[j]; }
            aF[f] = h;
        }
    }

    // K B-frag direct from global (L2-resident). Perfectly line-coalesced:
    // each instr = 16 rows x one fully-used 64B line.
    auto kfrag = [&](int kt, int ct, half8& b0, half8& b1) {
        if constexpr (WS) {
            const _Float16* p = Khb + (size_t)(kt * 64 + ct * 16 + ln) * D_ + qd * 8;
            b0 = *(const half8*)p;
            b1 = *(const half8*)(p + 32);
        } else {
            const float* p = Kb + (size_t)(kt * 64 + ct * 16 + ln) * D_ + qd * 8;
            f32x4 x0 = *(const f32x4*)p;
            f32x4 x1 = *(const f32x4*)(p + 4);
            f32x4 y0 = *(const f32x4*)(p + 32);
            f32x4 y1 = *(const f32x4*)(p + 36);
#pragma unroll
            for (int j = 0; j < 4; ++j) {
                b0[j] = (_Float16)x0[j]; b0[4 + j] = (_Float16)x1[j];
                b1[j] = (_Float16)y0[j]; b1[4 + j] = (_Float16)y1[j];
            }
        }
    };

    // V^T B-frag direct from global: v0[j] = V[kt*64 + qd*8 + j][d], d = c2*16+ln
    auto vfrag = [&](int kt, int c2, half8& v0, half8& v1) {
        if constexpr (WS) {
            const _Float16* p = Vthb + (size_t)(c2 * 16 + ln) * L_ + kt * 64 + qd * 8;
            v0 = *(const half8*)p;
            v1 = *(const half8*)(p + 32);
        } else {
            const float* p = Vb + (size_t)(kt * 64 + qd * 8) * D_ + (c2 * 16 + ln);
#pragma unroll
            for (int j = 0; j < 8; ++j) v0[j] = (_Float16)p[j * 64];
            p += 32 * 64;
#pragma unroll
            for (int j = 0; j < 8; ++j) v1[j] = (_Float16)p[j * 64];
        }
    };

    // ---- mask prefetch regs ----
    int mv[16];
    const int* maskbase = Mb + (size_t)(wv * 16 + qd * 4) * L_ + ln;
    auto loadM = [&](int kt) {
#pragma unroll
        for (int ct = 0; ct < 4; ++ct)
#pragma unroll
            for (int r = 0; r < 4; ++r)
                mv[ct * 4 + r] = maskbase[(size_t)r * L_ + kt * 64 + ct * 16];
    };

    // per-kt mask bits parked in the block's OWN result slab (16 KiB, exact fit;
    // each thread reads back only its own column; final barrier protects O overwrite).
    unsigned short* bitsSlab = (unsigned short*)Ob;

    // ================= PHASE 1: row sums (barrier-free) =================
    float lsum[4] = {0.f, 0.f, 0.f, 0.f};
    loadM(0);
    for (int kt = 0; kt < NKT; ++kt) {
        half8 kb[4][2];
#pragma unroll
        for (int ct = 0; ct < 4; ++ct) kfrag(kt, ct, kb[ct][0], kb[ct][1]);
        unsigned bits = 0;
#pragma unroll
        for (int i = 0; i < 16; ++i) bits |= (mv[i] > 0 ? 1u : 0u) << i;
        if (kt + 1 < NKT) loadM(kt + 1);          // HBM prefetch, a full iter of slack
        bitsSlab[kt * 256 + tid] = (unsigned short)bits;   // fire-and-forget
#pragma unroll
        for (int ct = 0; ct < 4; ++ct) {
            f32x4 acc = {0.f, 0.f, 0.f, 0.f};
            acc = mfma16f(aF[0], kb[ct][0], acc);
            acc = mfma16f(aF[1], kb[ct][1], acc);
#pragma unroll
            for (int r = 0; r < 4; ++r) {
                float bit = (float)((bits >> (ct * 4 + r)) & 1u);
                lsum[r] += bit * __expf(acc[r] * scale);
            }
        }
    }

    float invl[4];
#pragma unroll
    for (int r = 0; r < 4; ++r) {
        float v = lsum[r];
        v += __shfl_xor(v, 1);
        v += __shfl_xor(v, 2);
        v += __shfl_xor(v, 4);
        v += __shfl_xor(v, 8);
        invl[r] = v > 0.f ? 1.f / v : 0.f;   // fully-masked row -> zeros
    }

    // bits stores must be visible to this thread's own reads (in-order per thread after drain)
    asm volatile("s_waitcnt vmcnt(0)" ::: "memory");

    // ================= PHASE 2: recompute S, write att_w, accumulate O (barrier-free) ======
    f32x4 accO[4];
#pragma unroll
    for (int i = 0; i < 4; ++i) accO[i] = (f32x4){0.f, 0.f, 0.f, 0.f};

    unsigned bcur = bitsSlab[tid];
    for (int kt = 0; kt < NKT; ++kt) {
        unsigned bnext = (kt + 1 < NKT) ? (unsigned)bitsSlab[(kt + 1) * 256 + tid] : 0u;
        const unsigned bits = bcur;
        // QK^T + softmax -> Pbuf (own-wave rows only)
#pragma unroll
        for (int ct = 0; ct < 4; ++ct) {
            half8 b0, b1;
            kfrag(kt, ct, b0, b1);
            f32x4 acc = {0.f, 0.f, 0.f, 0.f};
            acc = mfma16f(aF[0], b0, acc);
            acc = mfma16f(aF[1], b1, acc);
#pragma unroll
            for (int r = 0; r < 4; ++r) {
                const int qrow = wv * 16 + qd * 4 + r;
                float bit = (float)((bits >> (ct * 4 + r)) & 1u);
                float p = bit * __expf(acc[r] * scale) * invl[r];
                Pbuf[qrow * PBP + ct * 16 + ln] = (_Float16)p;
            }
        }
        // A-frags of P (row = wv*16+ln, contiguous kk); compiler inserts lgkm wait
        half8 p0 = *(const half8*)&Pbuf[(wv * 16 + ln) * PBP + qd * 8];
        half8 p1 = *(const half8*)&Pbuf[(wv * 16 + ln) * PBP + 32 + qd * 8];
        {   // vectorized att_w store from the round-tripped fragments
            float* wp = Wb + (size_t)(wv * 16 + ln) * L_ + kt * 64;
            f32x4 s0, s1, s2, s3;
#pragma unroll
            for (int j = 0; j < 4; ++j) {
                s0[j] = (float)p0[j];     s1[j] = (float)p0[4 + j];
                s2[j] = (float)p1[j];     s3[j] = (float)p1[4 + j];
            }
            *(f32x4*)(wp + qd * 8)          = s0;
            *(f32x4*)(wp + qd * 8 + 4)      = s1;
            *(f32x4*)(wp + 32 + qd * 8)     = s2;
            *(f32x4*)(wp + 32 + qd * 8 + 4) = s3;
        }
        // PV: O += P * V, V^T frags straight from L2
#pragma unroll
        for (int c2 = 0; c2 < 4; ++c2) {
            half8 v0, v1;
            vfrag(kt, c2, v0, v1);
            accO[c2] = mfma16f(p0, v0, accO[c2]);
            accO[c2] = mfma16f(p1, v1, accO[c2]);
        }
        bcur = bnext;
    }

    // all waves must be done reading bitsSlab before O overwrites it
    __syncthreads();

    // ---- write result ----
#pragma unroll
    for (int c2 = 0; c2 < 4; ++c2)
#pragma unroll
        for (int r = 0; r < 4; ++r)
            Ob[(size_t)(wv * 16 + qd * 4 + r) * D_ + (c2 * 16 + ln)] = accO[c2][r];
}

extern "C" void kernel_launch(void* const* d_in, const int* in_sizes, int n_in,
                              void* d_out, int out_size, void* d_ws, size_t ws_size,
                              hipStream_t stream) {
    const float* q     = (const float*)d_in[0];
    const float* k     = (const float*)d_in[1];
    const float* v     = (const float*)d_in[2];
    const int*   valid = (const int*)d_in[3];
    const float* scale = (const float*)d_in[4];

    float* out_res  = (float*)d_out;
    float* out_attw = out_res + (size_t)2 * 16 * L_ * D_;

    const size_t elems = (size_t)2 * 16 * L_ * D_;           // 4,194,304
    const size_t need  = 2 * elems * sizeof(_Float16);        // 16.78 MB

    dim3 grid(2 * 16 * (L_ / QT));   // 1024
    dim3 block(256);

    if (ws_size >= need && d_ws != nullptr) {
        _Float16* Kh  = (_Float16*)d_ws;
        _Float16* Vth = Kh + elems;
        cvt_k<<<dim3(1024), dim3(256), 0, stream>>>(k, Kh);
        tr_v <<<dim3(1024), dim3(256), 0, stream>>>(v, Vth);
        attn_fused<true><<<grid, block, 0, stream>>>(q, k, v, valid, scale, Kh, Vth,
                                                     out_res, out_attw);
    } else {
        attn_fused<false><<<grid, block, 0, stream>>>(q, k, v, valid, scale, nullptr, nullptr,
                                                      out_res, out_attw);
    }
}